// Round 11
// baseline (223.460 us; speedup 1.0000x reference)
//
#include <hip/hip_runtime.h>
#include <math.h>

#define EMB_K   768
#define NH      96
#define SEQLEN  2048
#define NBATCH  16
#define MROWS   (NBATCH * SEQLEN)   // 32768

typedef __bf16 v8bf __attribute__((ext_vector_type(8)));
typedef float  v4f  __attribute__((ext_vector_type(4)));

// score scale folded into Q at qkv epilogue: (1/sqrt(96)) * log2(e)
#define QSCALE (0.10206207261596575f * 1.4426950408889634f)

#if __has_builtin(__builtin_amdgcn_global_load_lds)
#define ASYNC_LDS 1
#else
#define ASYNC_LDS 0
#endif

// ---------------------------------------------------------------------------
// Pack Wq/Wk/Wv (fp32 [768][96]) into bf16 B-fragment order. (unchanged)
// ---------------------------------------------------------------------------
__global__ __launch_bounds__(256) void pack_w(
    const float* __restrict__ Wq,
    const float* __restrict__ Wk,
    const float* __restrict__ Wv,
    __bf16* __restrict__ Wp)
{
    int t = blockIdx.x * 256 + threadIdx.x;
    if (t >= 3 * 24 * 6 * 64) return;
    int l  = t & 63;
    int fj = (t >> 6) % 6;
    int s  = ((t >> 6) / 6) % 24;
    int w  = (t >> 6) / (6 * 24);
    const float* W = (w == 0) ? Wq : ((w == 1) ? Wk : Wv);
    int n     = fj * 16 + (l & 15);
    int kbase = s * 32 + (l >> 4) * 8;
    __bf16 o[8];
    #pragma unroll
    for (int e = 0; e < 8; ++e)
        o[e] = (__bf16)W[(size_t)(kbase + e) * NH + n];
    *(v8bf*)(Wp + (size_t)t * 8) = *(v8bf*)o;
}

__device__ inline v8bf cvt8(const float4& a, const float4& b)
{
    v8bf r;
    r[0] = (__bf16)a.x; r[1] = (__bf16)a.y; r[2] = (__bf16)a.z; r[3] = (__bf16)a.w;
    r[4] = (__bf16)b.x; r[5] = (__bf16)b.y; r[6] = (__bf16)b.z; r[7] = (__bf16)b.w;
    return r;
}

// ---------------------------------------------------------------------------
// Fused QKV — ROUND 11 REWRITE: no global_load_lds. B(s+1) is staged via
// VGPR temps + ds_write_b128, so the barrier needs only lgkmcnt(0) + a fine
// vmcnt for the B temps — NOT the vmcnt(0) drain that global_load_lds forces.
// This lets the x stream (HBM-latency critical, ~1-3k cyc under load) stay
// outstanding ACROSS barriers: x is prefetched 2 slices deep in registers.
// Issue order per slice: B(s+1) loads first, x(s+2) loads second — vmcnt
// retires in order, so waiting for B temps leaves x in flight.
// LDS 50.7 KB -> 3 blocks/CU (launch_bounds(256,3), VGPR cap 170).
// ---------------------------------------------------------------------------
__global__ __launch_bounds__(256, 3) void qkv_fused(
    const float* __restrict__ x,
    const __bf16* __restrict__ Wp,
    __bf16* __restrict__ qk,
    __bf16* __restrict__ vt)
{
    __shared__ __bf16 Bs[2][18][512];   // 36.9 KB, double-buffered B frags
    __shared__ __bf16 VsT[96][72];      // 13.8 KB, V transpose bounce

    const int wave = threadIdx.x >> 6;
    const int lane = threadIdx.x & 63;
    const int mlow = lane & 15;
    const int kq   = lane >> 4;
    const int m0   = blockIdx.x * 64;
    const int r0   = m0 + wave * 16;

    const float* xr = x + (size_t)(r0 + mlow) * EMB_K + kq * 8;

    // frags owned by this wave: f = wave + 4*i  (waves 0,1: 5 frags; 2,3: 4)
    const int nf = (wave < 2) ? 5 : 4;

    v4f acc[3][6];
    #pragma unroll
    for (int w = 0; w < 3; ++w)
        #pragma unroll
        for (int j = 0; j < 6; ++j)
            acc[w][j] = (v4f)0.0f;

    // prologue: B(0) -> LDS, x(0), x(1) -> regs
    v8bf btmp[5];
    #pragma unroll
    for (int i = 0; i < 5; ++i)
        if (i < nf) {
            const int f = wave + 4 * i;
            btmp[i] = *(const v8bf*)(Wp + ((size_t)((f / 6) * 24) * 6 + (f % 6)) * 512
                                        + (size_t)lane * 8);
        }
    float4 xreg[2][2];
    xreg[0][0] = *(const float4*)(xr);
    xreg[0][1] = *(const float4*)(xr + 4);
    xreg[1][0] = *(const float4*)(xr + 32);
    xreg[1][1] = *(const float4*)(xr + 36);
    #pragma unroll
    for (int i = 0; i < 5; ++i)
        if (i < nf)
            *(v8bf*)&Bs[0][wave + 4 * i][(size_t)lane * 8] = btmp[i];
    __syncthreads();

    for (int s = 0; s < 24; ++s) {
        const int cur = s & 1;

        // consume x(s) (frees xreg[cur] for the s+2 prefetch)
        v8bf a = cvt8(xreg[cur][0], xreg[cur][1]);

        // issue B(s+1) loads FIRST (older in vmcnt FIFO)...
        if (s < 23) {
            #pragma unroll
            for (int i = 0; i < 5; ++i)
                if (i < nf) {
                    const int f = wave + 4 * i;
                    btmp[i] = *(const v8bf*)(Wp + ((size_t)((f / 6) * 24 + (s + 1)) * 6
                                                   + (f % 6)) * 512 + (size_t)lane * 8);
                }
        }
        // ...then x(s+2) (newer: stays outstanding when B temps are waited on)
        if (s < 22) {
            xreg[cur][0] = *(const float4*)(xr + (s + 2) * 32);
            xreg[cur][1] = *(const float4*)(xr + (s + 2) * 32 + 4);
        }

        // compute on Bs[cur] (covers part of the B-load latency)
        #pragma unroll
        for (int w = 0; w < 3; ++w)
            #pragma unroll
            for (int j = 0; j < 6; ++j) {
                v8bf bf = *(const v8bf*)&Bs[cur][w * 6 + j][(size_t)lane * 8];
                acc[w][j] = __builtin_amdgcn_mfma_f32_16x16x32_bf16(a, bf, acc[w][j], 0, 0, 0);
            }

        // stage B(s+1) into the other buffer (waits vmcnt only for B temps)
        if (s < 23) {
            #pragma unroll
            for (int i = 0; i < 5; ++i)
                if (i < nf)
                    *(v8bf*)&Bs[cur ^ 1][wave + 4 * i][(size_t)lane * 8] = btmp[i];
        }
        __syncthreads();   // lgkm drain only — x prefetch survives
    }

    // Q, K epilogue (Q pre-scaled by QSCALE)
    #pragma unroll
    for (int w = 0; w < 2; ++w) {
        __bf16* op = qk + (size_t)w * MROWS * NH;
        const float sc = (w == 0) ? QSCALE : 1.0f;
        #pragma unroll
        for (int j = 0; j < 6; ++j)
            #pragma unroll
            for (int r = 0; r < 4; ++r)
                op[(size_t)(r0 + kq * 4 + r) * NH + j * 16 + mlow] =
                    (__bf16)(acc[w][j][r] * sc);
    }
    // V -> LDS transposed, then coalesced store to vt[96][32768]
    #pragma unroll
    for (int j = 0; j < 6; ++j)
        #pragma unroll
        for (int r = 0; r < 4; ++r)
            VsT[j * 16 + mlow][wave * 16 + kq * 4 + r] = (__bf16)acc[2][j][r];
    __syncthreads();
    #pragma unroll
    for (int it = 0; it < 3; ++it) {
        int idx = it * 256 + threadIdx.x;
        int c = idx >> 3, g = idx & 7;
        *(v8bf*)(vt + (size_t)c * MROWS + m0 + g * 8) = *(const v8bf*)&VsT[c][g * 8];
    }
}

// ---------------------------------------------------------------------------
// MFMA causal flash attention — block-cooperative K/V staging.
// (byte-identical to round 10 — frozen for attribution)
// ---------------------------------------------------------------------------
__device__ const unsigned char JTAB[30] = {
    20, 24, 28, 32, 36, 40, 44, 45, 48, 49, 52, 53, 56, 57, 60, 61,
    0, 4, 8, 12, 16, 25, 29, 33, 37, 41, 50, 54, 58, 62
};

__global__ __launch_bounds__(256, 2) void attn_mfma(
    const __bf16* __restrict__ qk,
    const __bf16* __restrict__ vt,
    float* __restrict__ out,
    __bf16* __restrict__ Opart,
    float* __restrict__ ml)
{
    __shared__ __bf16 Kf[2][12][512];
    __shared__ __bf16 Vf[2][12][512];
    __shared__ __bf16 Ps[4][16][72];

    const int bid = blockIdx.x;
    const int b   = bid & 15;
    const int j   = bid >> 4;
    const int enc = JTAB[j];
    const int qt  = enc >> 2;
    const int c0  = enc & 3;
    const int ntiles = 2 * qt + 2;
    const int t0  = c0 * 12;
    const int t1  = (t0 + 12 < ntiles) ? (t0 + 12) : ntiles;
    const int nch = (ntiles + 11) / 12;

    const int wave = threadIdx.x >> 6;
    const int lane = threadIdx.x & 63;
    const int mlow = lane & 15;
    const int kq   = lane >> 4;
    const int qw0  = qt * 128 + wave * 32;

    const __bf16* qp  = qk + (size_t)b * SEQLEN * NH;
    const __bf16* kp  = qk + (size_t)MROWS * NH + (size_t)b * SEQLEN * NH;
    const __bf16* vtp = vt + (size_t)b * SEQLEN;

    v8bf qa[2][3];
    #pragma unroll
    for (int g2 = 0; g2 < 2; ++g2)
        #pragma unroll
        for (int s = 0; s < 3; ++s)
            qa[g2][s] = *(const v8bf*)(qp + (size_t)(qw0 + g2 * 16 + mlow) * NH
                                          + s * 32 + kq * 8);

    v4f lsum[2];
    v4f O[2][6];
    #pragma unroll
    for (int g2 = 0; g2 < 2; ++g2) {
        lsum[g2] = (v4f)0.0f;
        #pragma unroll
        for (int jj = 0; jj < 6; ++jj) O[g2][jj] = (v4f)0.0f;
    }

    auto stage = [&](int t, int buf) {
        const int k0 = t * 64;
        #pragma unroll
        for (int i = 0; i < 6; ++i) {
            const int f = wave * 6 + i;
            const __bf16* src;
            __bf16* dst;
            if (f < 12) {
                const int t4 = f / 3, s = f - t4 * 3;
                src = kp + (size_t)(k0 + t4 * 16 + mlow) * NH + s * 32 + kq * 8;
                dst = &Kf[buf][f][0];
            } else {
                const int fv = f - 12;
                const int jj = fv >> 1, h = fv & 1;
                src = vtp + (size_t)(jj * 16 + mlow) * MROWS + k0 + h * 32 + kq * 8;
                dst = &Vf[buf][fv][0];
            }
#if ASYNC_LDS
            __builtin_amdgcn_global_load_lds(
                (const __attribute__((address_space(1))) void*)src,
                (__attribute__((address_space(3))) void*)dst,
                16, 0, 0);
#else
            *(v8bf*)(dst + (size_t)lane * 8) = *(const v8bf*)src;
#endif
        }
    };

    stage(t0, 0);
    __syncthreads();

    for (int t = t0; t < t1; ++t) {
        const int buf = (t - t0) & 1;
        if (t + 1 < t1) stage(t + 1, buf ^ 1);
        const int k0 = t * 64;

        if (k0 <= qw0 + 31) {
            const bool msk = (k0 + 63 > qw0);
            #pragma unroll
            for (int g2 = 0; g2 < 2; ++g2) {
                float s2[4][4];
                #pragma unroll
                for (int t4 = 0; t4 < 4; ++t4) {
                    v4f sa = (v4f)0.0f;
                    #pragma unroll
                    for (int s = 0; s < 3; ++s) {
                        v8bf kb = *(const v8bf*)&Kf[buf][t4 * 3 + s][(size_t)lane * 8];
                        sa = __builtin_amdgcn_mfma_f32_16x16x32_bf16(qa[g2][s], kb, sa, 0, 0, 0);
                    }
                    #pragma unroll
                    for (int r = 0; r < 4; ++r) s2[t4][r] = sa[r];
                }
                if (msk) {
                    #pragma unroll
                    for (int t4 = 0; t4 < 4; ++t4)
                        #pragma unroll
                        for (int r = 0; r < 4; ++r)
                            if (k0 + t4 * 16 + mlow > qw0 + g2 * 16 + kq * 4 + r)
                                s2[t4][r] = -1e20f;
                }

                v4f pvv[4];
                #pragma unroll
                for (int t4 = 0; t4 < 4; ++t4)
                    #pragma unroll
                    for (int r = 0; r < 4; ++r)
                        pvv[t4][r] = exp2f(s2[t4][r]);
                lsum[g2] += (pvv[0] + pvv[1]) + (pvv[2] + pvv[3]);

                #pragma unroll
                for (int t4 = 0; t4 < 4; ++t4)
                    #pragma unroll
                    for (int r = 0; r < 4; ++r)
                        Ps[wave][kq * 4 + r][t4 * 16 + mlow] = (__bf16)pvv[t4][r];

                v8bf pa0 = *(const v8bf*)&Ps[wave][mlow][kq * 8];
                v8bf pa1 = *(const v8bf*)&Ps[wave][mlow][32 + kq * 8];

                #pragma unroll
                for (int jj = 0; jj < 6; ++jj) {
                    v8bf vb0 = *(const v8bf*)&Vf[buf][jj * 2][(size_t)lane * 8];
                    v8bf vb1 = *(const v8bf*)&Vf[buf][jj * 2 + 1][(size_t)lane * 8];
                    O[g2][jj] = __builtin_amdgcn_mfma_f32_16x16x32_bf16(pa0, vb0, O[g2][jj], 0, 0, 0);
                    O[g2][jj] = __builtin_amdgcn_mfma_f32_16x16x32_bf16(pa1, vb1, O[g2][jj], 0, 0, 0);
                }
            }
        }
        __syncthreads();
    }

    #pragma unroll
    for (int off = 1; off < 16; off <<= 1)
        #pragma unroll
        for (int g2 = 0; g2 < 2; ++g2)
            #pragma unroll
            for (int r = 0; r < 4; ++r)
                lsum[g2][r] += __shfl_xor(lsum[g2][r], off);

    if (nch == 1) {
        #pragma unroll
        for (int g2 = 0; g2 < 2; ++g2)
            #pragma unroll
            for (int r = 0; r < 4; ++r) {
                float inv = 1.0f / lsum[g2][r];
                float* orow = out + ((size_t)b * SEQLEN + qw0 + g2 * 16 + kq * 4 + r) * NH;
                #pragma unroll
                for (int jj = 0; jj < 6; ++jj)
                    orow[jj * 16 + mlow] = O[g2][jj][r] * inv;
            }
    } else {
        const int e = (b * 10 + (qt - 6)) * 3 + c0;
        __bf16* Pp = Opart + (size_t)e * 12288;
        #pragma unroll
        for (int g2 = 0; g2 < 2; ++g2)
            #pragma unroll
            for (int r = 0; r < 4; ++r) {
                const int row = wave * 32 + g2 * 16 + kq * 4 + r;
                float inv = 1.0f / lsum[g2][r];
                #pragma unroll
                for (int jj = 0; jj < 6; ++jj)
                    Pp[row * 96 + jj * 16 + mlow] = (__bf16)(O[g2][jj][r] * inv);
                if (mlow == 0) {
                    ml[(size_t)e * 256 + row * 2]     = 0.0f;
                    ml[(size_t)e * 256 + row * 2 + 1] = lsum[g2][r];
                }
            }
    }
}

// ---------------------------------------------------------------------------
// Merge 2..3 partials per (b, qt>=6). (unchanged)
// ---------------------------------------------------------------------------
__global__ __launch_bounds__(256) void attn_combine(
    const __bf16* __restrict__ Opart,
    const float* __restrict__ ml,
    float* __restrict__ out)
{
    __shared__ float wsh[3][128];
    const int b   = blockIdx.x & 15;
    const int qr  = blockIdx.x >> 4;
    const int qt  = 6 + qr;
    const int nch = (qt >= 12) ? 3 : 2;
    const int e0  = (b * 10 + qr) * 3;
    const int tid = threadIdx.x;

    if (tid < 128) {
        float m[3], l[3];
        float M = -INFINITY;
        #pragma unroll
        for (int c = 0; c < 3; ++c) {
            if (c < nch) {
                m[c] = ml[(size_t)(e0 + c) * 256 + tid * 2];
                l[c] = ml[(size_t)(e0 + c) * 256 + tid * 2 + 1];
            } else { m[c] = -INFINITY; l[c] = 0.0f; }
            M = fmaxf(M, m[c]);
        }
        float a[3], s = 0.0f;
        #pragma unroll
        for (int c = 0; c < 3; ++c) { a[c] = exp2f(m[c] - M) * l[c]; s += a[c]; }
        float inv = 1.0f / s;
        #pragma unroll
        for (int c = 0; c < 3; ++c) wsh[c][tid] = a[c] * inv;
    }
    __syncthreads();

    float* op = out + ((size_t)b * SEQLEN + (size_t)qt * 128) * NH;
    #pragma unroll
    for (int it = 0; it < 6; ++it) {
        int idx = it * 256 + tid;
        int row = idx / 12;
        int off = idx * 8;
        float acc[8];
        #pragma unroll
        for (int k = 0; k < 8; ++k) acc[k] = 0.0f;
        #pragma unroll
        for (int c = 0; c < 3; ++c) {
            if (c < nch) {
                v8bf p = *(const v8bf*)(Opart + (size_t)(e0 + c) * 12288 + off);
                float w = wsh[c][row];
                #pragma unroll
                for (int k = 0; k < 8; ++k) acc[k] += w * (float)p[k];
            }
        }
        *(float4*)(op + off)     = make_float4(acc[0], acc[1], acc[2], acc[3]);
        *(float4*)(op + off + 4) = make_float4(acc[4], acc[5], acc[6], acc[7]);
    }
}

// ---------------------------------------------------------------------------
extern "C" void kernel_launch(void* const* d_in, const int* in_sizes, int n_in,
                              void* d_out, int out_size, void* d_ws, size_t ws_size,
                              hipStream_t stream)
{
    (void)in_sizes; (void)n_in; (void)out_size; (void)ws_size;
    const float* x  = (const float*)d_in[0];
    const float* Wq = (const float*)d_in[1];
    const float* Wk = (const float*)d_in[2];
    const float* Wv = (const float*)d_in[3];
    float* out = (float*)d_out;

    __bf16* qk    = (__bf16*)d_ws;                          // 12.58 MB (Q,K)
    __bf16* vt    = qk + (size_t)2 * MROWS * NH;            //  6.29 MB (V^T)
    __bf16* Wp    = vt + (size_t)NH * MROWS;                //  0.44 MB
    __bf16* Opart = Wp + (size_t)3 * 24 * 6 * 512;          // 11.80 MB (bf16)
    float*  ml    = (float*)(Opart + (size_t)480 * 12288);  //  0.49 MB

    pack_w<<<(3 * 24 * 6 * 64 + 255) / 256, 256, 0, stream>>>(Wq, Wk, Wv, Wp);
    qkv_fused<<<MROWS / 64, 256, 0, stream>>>(x, Wp, qk, vt);
    attn_mfma<<<dim3(480), 256, 0, stream>>>(qk, vt, out, Opart, ml);
    attn_combine<<<dim3(160), 256, 0, stream>>>(Opart, ml, out);
}